// Round 10
// baseline (4139.253 us; speedup 1.0000x reference)
//
#include <hip/hip_runtime.h>
#include <hip/hip_bf16.h>
#include <hip/hip_fp16.h>

using half_t = _Float16;
typedef __attribute__((ext_vector_type(8))) _Float16 f16x8;  // 8 fp16 = 4 VGPRs (MFMA frag)
typedef __attribute__((ext_vector_type(4))) _Float16 f16x4;
typedef __attribute__((ext_vector_type(4))) float f32x4;

#define LN_EPS 1e-5f
#define AGENT __HIP_MEMORY_SCOPE_AGENT

// async global->LDS, 16B per lane. gptr is PER-LANE, ldsbase is wave-uniform;
// HW writes ldsbase + lane*16.  [m97/m173 pattern]
__device__ inline void gll16(const void* g, void* ldsbase) {
    __builtin_amdgcn_global_load_lds(
        (const __attribute__((address_space(1))) void*)g,
        (__attribute__((address_space(3))) void*)ldsbase, 16, 0, 0);
}

// ---------------------------------------------------------------------------
// Wave-scope LN-LSTM cell: one 64-lane wave owns one batch row (16 elems/lane).
// pre reads + c-state r/w are normal cached (cross-launch coherent);
// h stores are agent-scope relaxed atomics (write-through, consumed in-launch).
// ---------------------------------------------------------------------------
__device__ inline void cell_wave2(
    int b, int l,
    const half_t* __restrict__ pa, const half_t* __restrict__ pb,
    const float* __restrict__ bias,
    float* __restrict__ cst, half_t* __restrict__ hs,
    float* __restrict__ hf, bool final_step)
{
    float cn[16], og[16];
    float s = 0.f;
    #pragma unroll
    for (int j = 0; j < 4; ++j) {
        const int e = j*256 + l*4;
        const size_t pbase = (size_t)b*4096 + e;
        f16x4 a0 = *(const f16x4*)&pa[pbase];
        f16x4 a1 = *(const f16x4*)&pa[pbase + 1024];
        f16x4 a2 = *(const f16x4*)&pa[pbase + 2048];
        f16x4 a3 = *(const f16x4*)&pa[pbase + 3072];
        f16x4 q0 = *(const f16x4*)&pb[pbase];
        f16x4 q1 = *(const f16x4*)&pb[pbase + 1024];
        f16x4 q2 = *(const f16x4*)&pb[pbase + 2048];
        f16x4 q3 = *(const f16x4*)&pb[pbase + 3072];
        float4 b0 = *(const float4*)&bias[e];
        float4 b1v = *(const float4*)&bias[1024 + e];
        float4 b2v = *(const float4*)&bias[2048 + e];
        float4 b3v = *(const float4*)&bias[3072 + e];
        float4 c4 = *(const float4*)&cst[(size_t)b*1024 + e];
        const float* bp0 = (const float*)&b0;
        const float* bp1 = (const float*)&b1v;
        const float* bp2 = (const float*)&b2v;
        const float* bp3 = (const float*)&b3v;
        const float* cp  = (const float*)&c4;
        #pragma unroll
        for (int k = 0; k < 4; ++k) {
            float pi = (float)a0[k] + (float)q0[k] + bp0[k];
            float pf = (float)a1[k] + (float)q1[k] + bp1[k];
            float po = (float)a2[k] + (float)q2[k] + bp2[k];
            float pc = (float)a3[k] + (float)q3[k] + bp3[k];
            float ig = 1.f / (1.f + expf(-pi));
            float fg = 1.f / (1.f + expf(-pf));
            og[j*4+k] = 1.f / (1.f + expf(-po));
            float ct = tanhf(pc);
            float cv = fg * cp[k] + ig * ct;
            cn[j*4+k] = cv; s += cv;
        }
    }
    #pragma unroll
    for (int off = 1; off < 64; off <<= 1) s += __shfl_xor(s, off, 64);
    const float mu = s * (1.f/1024.f);
    float vs = 0.f;
    #pragma unroll
    for (int i = 0; i < 16; ++i) { float d = cn[i] - mu; vs += d*d; }
    #pragma unroll
    for (int off = 1; off < 64; off <<= 1) vs += __shfl_xor(vs, off, 64);
    const float rs = rsqrtf(vs * (1.f/1024.f) + LN_EPS);
    #pragma unroll
    for (int j = 0; j < 4; ++j) {
        const int e = j*256 + l*4;
        union { unsigned long long u; f16x4 h; } hp;
        float4 hf4, c4;
        float* hfp = (float*)&hf4; float* cp = (float*)&c4;
        #pragma unroll
        for (int k = 0; k < 4; ++k) {
            float cv = (cn[j*4+k] - mu) * rs;
            float hv = og[j*4+k] * tanhf(cv);
            hp.h[k] = (half_t)hv;
            hfp[k] = hv; cp[k] = cv;
        }
        *(float4*)&cst[(size_t)b*1024 + e] = c4;
        __hip_atomic_store((unsigned long long*)&hs[(size_t)b*1024 + e], hp.u,
                           __ATOMIC_RELAXED, AGENT);
        if (final_step) *(float4*)&hf[(size_t)b*1024 + e] = hf4;
    }
}

// ---------------------------------------------------------------------------
// One-step kernel. 512 WGs x 256 thr = 2 WGs/CU, all co-resident.
//   WGs 0..127: cell1(st), flag; 128..255: cell2(st-1), flag.
//   All WGs then one 128x128x1024 GEMM tile:
//     z0: preA2=h0@wx2^T  z1: preB2=h1@wh2^T  z2: preB1(t+1)=h0@wh1^T
//     z3: preA1(t+1)=X(t+1)@wx1^T  (no deps on this step's cells: no wait,
//         plain global_load_lds for A, step-parity double-buffered output)
//   h-operand (z0..z2): 8B agent-scope relaxed atomic loads (COMPILER-
//   generated waits — the R9 inline-asm load was rule-#18-unsafe and NaN'd).
// ---------------------------------------------------------------------------
__global__ __launch_bounds__(256, 2) void step_kernel(
    const half_t* __restrict__ X,
    const half_t* __restrict__ wx1c, const half_t* __restrict__ wx2c,
    const half_t* __restrict__ wh1t, const half_t* __restrict__ wh2t,
    const float* __restrict__ b1, const float* __restrict__ b2,
    half_t* __restrict__ preA1a, half_t* __restrict__ preA1b,
    half_t* __restrict__ preA2,
    half_t* __restrict__ preB1, half_t* __restrict__ preB2,
    half_t* __restrict__ h0s, half_t* __restrict__ h1s,
    float* __restrict__ h0f, float* __restrict__ h1f,
    float* __restrict__ c0, float* __restrict__ c1,
    int* __restrict__ flags, int st)
{
    __shared__ __align__(16) unsigned char sA[2][16384];
    __shared__ __align__(16) unsigned char sB[2][16384];

    const int wg = blockIdx.x;
    const int t = threadIdx.x, l = t & 63, w = t >> 6;

    const half_t* preA1_rd = (st & 1) ? preA1b : preA1a;   // cell1 input
    half_t*       preA1_wr = (st & 1) ? preA1a : preA1b;   // z3 output (t+1)

    // ---- phase A: cells ----
    if (wg < 128) {
        cell_wave2(wg*4 + w, l, preA1_rd, preB1, b1, c0, h0s, h0f, st == 63);
        __syncthreads();
        if (t == 0)
            __hip_atomic_fetch_add(&flags[st*16 + (wg >> 5)], 1, __ATOMIC_RELEASE, AGENT);
    } else if (wg < 256) {
        if (st > 0)
            cell_wave2((wg-128)*4 + w, l, preA2, preB2, b2, c1, h1s, h1f, false);
        __syncthreads();
        if (t == 0)
            __hip_atomic_fetch_add(&flags[st*16 + 8 + ((wg-128) >> 5)], 1, __ATOMIC_RELEASE, AGENT);
    }

    // ---- decode GEMM tile: wg = ylo + 8*(x + 4*(z + 4*yhi)) ----
    const int ylo = wg & 7;
    int r = wg >> 3;
    const int x = r & 3; r >>= 2;
    const int z = r & 3; r >>= 2;
    const int y = ylo + 8 * r;
    const bool zx = (z == 3);

    if (zx && st == 63) return;          // t+1 doesn't exist (after cells!)

    const half_t* A; const half_t* B; half_t* C; size_t lda;
    if (z == 0)      { A = h0s; lda = 1024; B = wx2c; C = preA2; }
    else if (z == 1) { A = h1s; lda = 1024; B = wh2t; C = preB2; }
    else if (z == 2) { A = h0s; lda = 1024; B = wh1t; C = preB1; }
    else { A = X + (size_t)(st+1) * 1024; lda = 65536; B = wx1c; C = preA1_wr; }

    const int wr = (w >> 1) * 64, wc = (w & 1) * 64;
    const int rowbase = x * 128, colbase = y * 128;

    int srow[4], sch[4];
    #pragma unroll
    for (int i = 0; i < 4; ++i) {
        int s = (w*4 + i)*64 + l;
        srow[i] = s >> 3;
        sch[i]  = ((s & 7) ^ (srow[i] & 7)) * 8;
    }

    // B (weights) K-tile 0: prefetch BEFORE the flag spin
    #pragma unroll
    for (int i = 0; i < 4; ++i)
        gll16(B + (size_t)(colbase+srow[i])*1024 + sch[i], &sB[0][(w*4+i)*1024]);

    if (!zx) {   // wait for BOTH cell sets of this x-block (data + WAR safety)
        while (__hip_atomic_load(&flags[st*16 + x], __ATOMIC_RELAXED, AGENT) < 32)
            __builtin_amdgcn_s_sleep(1);
        while (__hip_atomic_load(&flags[st*16 + 8 + x], __ATOMIC_RELAXED, AGENT) < 32)
            __builtin_amdgcn_s_sleep(1);
        __builtin_amdgcn_sched_barrier(0);
    }

    f32x4 acc[4][4];
    #pragma unroll
    for (int m = 0; m < 4; ++m)
        #pragma unroll
        for (int n = 0; n < 4; ++n) acc[m][n] = (f32x4)(0.f);

    unsigned long long av[8];
    // A K-tile 0
    if (zx) {
        #pragma unroll
        for (int i = 0; i < 4; ++i)
            gll16(A + (size_t)(rowbase+srow[i])*lda + sch[i], &sA[0][(w*4+i)*1024]);
    } else {
        #pragma unroll
        for (int i = 0; i < 4; ++i) {
            const unsigned long long* p =
                (const unsigned long long*)(A + (size_t)(rowbase+srow[i])*1024 + sch[i]);
            av[2*i]   = __hip_atomic_load(p,   __ATOMIC_RELAXED, AGENT);
            av[2*i+1] = __hip_atomic_load(p+1, __ATOMIC_RELAXED, AGENT);
        }
        #pragma unroll
        for (int i = 0; i < 4; ++i) {
            unsigned long long* q = (unsigned long long*)&sA[0][((w*4+i)*64 + l)*16];
            q[0] = av[2*i]; q[1] = av[2*i+1];
        }
    }

    for (int kt = 0; kt < 16; ++kt) {
        const int buf = kt & 1;
        __syncthreads();                       // buf ready; WAR-safe for buf^1
        const bool more = (kt + 1 < 16);
        if (more) {
            const int ko = (kt + 1) * 64;
            #pragma unroll
            for (int i = 0; i < 4; ++i)
                gll16(B + (size_t)(colbase+srow[i])*1024 + ko + sch[i], &sB[buf^1][(w*4+i)*1024]);
            if (zx) {
                #pragma unroll
                for (int i = 0; i < 4; ++i)
                    gll16(A + (size_t)(rowbase+srow[i])*lda + ko + sch[i], &sA[buf^1][(w*4+i)*1024]);
            } else {
                #pragma unroll
                for (int i = 0; i < 4; ++i) {
                    const unsigned long long* p =
                        (const unsigned long long*)(A + (size_t)(rowbase+srow[i])*1024 + ko + sch[i]);
                    av[2*i]   = __hip_atomic_load(p,   __ATOMIC_RELAXED, AGENT);
                    av[2*i+1] = __hip_atomic_load(p+1, __ATOMIC_RELAXED, AGENT);
                }
            }
        }
        #pragma unroll
        for (int kk = 0; kk < 2; ++kk) {
            const int chunk = kk*4 + (l >> 4);
            f16x8 bfr[4];
            #pragma unroll
            for (int n = 0; n < 4; ++n) {
                int rowb = wc + n*16 + (l & 15);
                bfr[n] = *(const f16x8*)&sB[buf][rowb*128 + ((chunk ^ (rowb & 7)) << 4)];
            }
            #pragma unroll
            for (int m = 0; m < 4; ++m) {
                int rowa = wr + m*16 + (l & 15);
                f16x8 af = *(const f16x8*)&sA[buf][rowa*128 + ((chunk ^ (rowa & 7)) << 4)];
                #pragma unroll
                for (int n = 0; n < 4; ++n)
                    acc[m][n] = __builtin_amdgcn_mfma_f32_16x16x32_f16(af, bfr[n], acc[m][n], 0, 0, 0);
            }
        }
        if (!zx && more) {                     // late ds_write (compiler waits on av)
            #pragma unroll
            for (int i = 0; i < 4; ++i) {
                unsigned long long* q = (unsigned long long*)&sA[buf^1][((w*4+i)*64 + l)*16];
                q[0] = av[2*i]; q[1] = av[2*i+1];
            }
        }
    }

    // epilogue: C/D layout col = lane&15, row = (lane>>4)*4 + reg  [m89/m91]
    #pragma unroll
    for (int m = 0; m < 4; ++m) {
        int row0 = rowbase + wr + m*16 + (l >> 4)*4;
        #pragma unroll
        for (int n = 0; n < 4; ++n) {
            int col = colbase + wc + n*16 + (l & 15);
            #pragma unroll
            for (int r2 = 0; r2 < 4; ++r2)
                C[(size_t)(row0+r2)*4096 + col] = (half_t)acc[m][n][r2];
        }
    }
}

// final cell2(63)
__global__ __launch_bounds__(256) void cells_final(
    const half_t* __restrict__ preA2, const half_t* __restrict__ preB2,
    const float* __restrict__ b2,
    float* __restrict__ c1, half_t* __restrict__ h1s, float* __restrict__ h1f)
{
    cell_wave2(blockIdx.x*4 + (threadIdx.x >> 6), threadIdx.x & 63,
               preA2, preB2, b2, c1, h1s, h1f, true);
}

struct GArgs {
    const half_t* A; const half_t* B; const float* bias; void* C;
    int lda, ldb, K, ldc, outhalf;
};

// ---------------------------------------------------------------------------
// Multi-set fp16 GEMM (prologue / fallback / fc2): up to 3 independent C=A*B^T.
// ---------------------------------------------------------------------------
__global__ __launch_bounds__(256) void gemm_ms(GArgs g0, GArgs g1, GArgs g2,
                                               int gx, int gz)
{
    const int d   = blockIdx.x;
    const int ylo = d & 7;
    int r   = d >> 3;
    const int x  = r % gx;  r /= gx;
    const int z  = r % gz;
    const int y  = ylo + 8 * (r / gz);

    const GArgs g = (z == 0) ? g0 : (z == 1 ? g1 : g2);

    __shared__ __align__(16) unsigned char sA[2][16384];
    __shared__ __align__(16) unsigned char sB[2][16384];

    const int t  = threadIdx.x;
    const int l  = t & 63;
    const int w  = t >> 6;
    const int wr = (w >> 1) * 64;
    const int wc = (w & 1)  * 64;
    const int rowbase = x * 128;
    const int colbase = y * 128;

    f32x4 acc[4][4];
    #pragma unroll
    for (int m = 0; m < 4; ++m)
        #pragma unroll
        for (int n = 0; n < 4; ++n) acc[m][n] = (f32x4)(0.f);

    int srow[4], sch[4];
    #pragma unroll
    for (int i = 0; i < 4; ++i) {
        int s = (w*4 + i)*64 + l;
        srow[i] = s >> 3;
        sch[i]  = ((s & 7) ^ (srow[i] & 7)) * 8;
    }

    const int nkt = g.K >> 6;

    auto stage = [&](int kt, int buf) {
        const int ko = kt * 64;
        #pragma unroll
        for (int i = 0; i < 4; ++i) {
            gll16(g.A + (size_t)(rowbase+srow[i])*g.lda + ko + sch[i], &sA[buf][(w*4+i)*1024]);
            gll16(g.B + (size_t)(colbase+srow[i])*g.ldb + ko + sch[i], &sB[buf][(w*4+i)*1024]);
        }
    };

    stage(0, 0);
    for (int kt = 0; kt < nkt; ++kt) {
        const int buf = kt & 1;
        __syncthreads();
        if (kt + 1 < nkt) stage(kt + 1, buf ^ 1);
        #pragma unroll
        for (int kk = 0; kk < 2; ++kk) {
            const int chunk = kk*4 + (l >> 4);
            f16x8 bfr[4];
            #pragma unroll
            for (int n = 0; n < 4; ++n) {
                int rowb = wc + n*16 + (l & 15);
                bfr[n] = *(const f16x8*)&sB[buf][rowb*128 + ((chunk ^ (rowb & 7)) << 4)];
            }
            #pragma unroll
            for (int m = 0; m < 4; ++m) {
                int rowa = wr + m*16 + (l & 15);
                f16x8 af = *(const f16x8*)&sA[buf][rowa*128 + ((chunk ^ (rowa & 7)) << 4)];
                #pragma unroll
                for (int n = 0; n < 4; ++n)
                    acc[m][n] = __builtin_amdgcn_mfma_f32_16x16x32_f16(af, bfr[n], acc[m][n], 0, 0, 0);
            }
        }
    }

    #pragma unroll
    for (int m = 0; m < 4; ++m) {
        int row0 = rowbase + wr + m*16 + (l >> 4)*4;
        #pragma unroll
        for (int n = 0; n < 4; ++n) {
            int col = colbase + wc + n*16 + (l & 15);
            float bv = g.bias ? g.bias[col] : 0.f;
            #pragma unroll
            for (int r2 = 0; r2 < 4; ++r2) {
                float v = acc[m][n][r2] + bv;
                if (g.outhalf) ((half_t*)g.C)[(size_t)(row0+r2)*g.ldc + col] = (half_t)v;
                else           ((float*)g.C)[(size_t)(row0+r2)*g.ldc + col] = v;
            }
        }
    }
}

// ---------------------------------------------------------------------------
__global__ __launch_bounds__(256) void transpose_wh_cvt(
    const float* __restrict__ wh1, const float* __restrict__ wh2,
    half_t* __restrict__ o1, half_t* __restrict__ o2)
{
    __shared__ float tile[64][65];
    const int z = blockIdx.z;
    const float* src = (z < 4 ? wh1 : wh2) + (size_t)(z & 3) * 1024 * 1024;
    half_t*      dst = (z < 4 ? o1  : o2 ) + (size_t)(z & 3) * 1024 * 1024;
    const int kb = blockIdx.x * 64, nb = blockIdx.y * 64;
    const int t = threadIdx.x;
    #pragma unroll
    for (int i = 0; i < 16; ++i) {
        int idx = t + i*256, r = idx >> 6, c = idx & 63;
        tile[r][c] = src[(size_t)(kb + r)*1024 + nb + c];
    }
    __syncthreads();
    #pragma unroll
    for (int i = 0; i < 16; ++i) {
        int idx = t + i*256, r = idx >> 6, c = idx & 63;
        dst[(size_t)(nb + r)*1024 + kb + c] = (half_t)tile[c][r];
    }
}

__global__ __launch_bounds__(256) void cvt_f32_f16(
    const float* __restrict__ in, half_t* __restrict__ out, int n8)
{
    int i = blockIdx.x * 256 + threadIdx.x;
    if (i >= n8) return;
    float4 lo = ((const float4*)in)[2*i];
    float4 hi = ((const float4*)in)[2*i + 1];
    union { uint4 v; half_t h[8]; } r;
    r.h[0]=(half_t)lo.x; r.h[1]=(half_t)lo.y; r.h[2]=(half_t)lo.z; r.h[3]=(half_t)lo.w;
    r.h[4]=(half_t)hi.x; r.h[5]=(half_t)hi.y; r.h[6]=(half_t)hi.z; r.h[7]=(half_t)hi.w;
    ((uint4*)out)[i] = r.v;
}

__global__ __launch_bounds__(256) void pack_out(
    const float* __restrict__ h0, const float* __restrict__ h1,
    const float* __restrict__ c0, const float* __restrict__ c1, float* __restrict__ out)
{
    const int NSZ = 512 * 1024;
    int i = blockIdx.x * 256 + threadIdx.x;
    out[NSZ     + i] = h0[i];
    out[2*NSZ   + i] = h1[i];
    out[3*NSZ   + i] = c0[i];
    out[4*NSZ   + i] = c1[i];
}

// fallback cell kernel (ws too small path)
__device__ inline float block_sum(float v, float* sred) {
    #pragma unroll
    for (int off = 32; off; off >>= 1) v += __shfl_down(v, off, 64);
    __syncthreads();
    if ((threadIdx.x & 63) == 0) sred[threadIdx.x >> 6] = v;
    __syncthreads();
    return sred[0] + sred[1] + sred[2] + sred[3];
}

__global__ __launch_bounds__(256) void lstm_cell(
    const half_t* __restrict__ preA, const half_t* __restrict__ preB,
    const float* __restrict__ bias,
    float* __restrict__ c_state, half_t* __restrict__ h16, float* __restrict__ h32)
{
    __shared__ float sred[4];
    const int b = blockIdx.x, t = threadIdx.x;
    const int hi = t * 4;
    const size_t pb = (size_t)b * 4096 + hi;
    const size_t cb = (size_t)b * 1024 + hi;

    float pre[4][4];
    #pragma unroll
    for (int g = 0; g < 4; ++g) {
        f16x4 a4 = *(const f16x4*)&preA[pb + g*1024];
        f16x4 v4 = *(const f16x4*)&preB[pb + g*1024];
        float4 bs = *(const float4*)&bias[g*1024 + hi];
        pre[g][0] = (float)a4[0] + (float)v4[0] + bs.x;
        pre[g][1] = (float)a4[1] + (float)v4[1] + bs.y;
        pre[g][2] = (float)a4[2] + (float)v4[2] + bs.z;
        pre[g][3] = (float)a4[3] + (float)v4[3] + bs.w;
    }
    float4 c4 = *(const float4*)&c_state[cb];
    float co[4] = {c4.x, c4.y, c4.z, c4.w};

    float cn[4], og[4], s = 0.f;
    #pragma unroll
    for (int j = 0; j < 4; ++j) {
        float ig = 1.f / (1.f + expf(-pre[0][j]));
        float fg = 1.f / (1.f + expf(-pre[1][j]));
        og[j]    = 1.f / (1.f + expf(-pre[2][j]));
        float ct = tanhf(pre[3][j]);
        cn[j] = fg * co[j] + ig * ct;
        s += cn[j];
    }
    float mu  = block_sum(s, sred) * (1.f/1024.f);
    float vs = 0.f;
    #pragma unroll
    for (int j = 0; j < 4; ++j) { float d = cn[j] - mu; vs += d*d; }
    float var = block_sum(vs, sred) * (1.f/1024.f);
    float rs  = rsqrtf(var + LN_EPS);

    float4 cw, hw; f16x4 h16w;
    float cvv[4], hvv[4];
    #pragma unroll
    for (int j = 0; j < 4; ++j) {
        cvv[j] = (cn[j] - mu) * rs;
        hvv[j] = og[j] * tanhf(cvv[j]);
        h16w[j] = (half_t)hvv[j];
    }
    cw.x=cvv[0]; cw.y=cvv[1]; cw.z=cvv[2]; cw.w=cvv[3];
    hw.x=hvv[0]; hw.y=hvv[1]; hw.z=hvv[2]; hw.w=hvv[3];
    *(float4*)&c_state[cb] = cw;
    *(f16x4*)&h16[cb]      = h16w;
    *(float4*)&h32[cb]     = hw;
}

extern "C" void kernel_launch(void* const* d_in, const int* in_sizes, int n_in,
                              void* d_out, int out_size, void* d_ws, size_t ws_size,
                              hipStream_t stream)
{
    const float* obs   = (const float*)d_in[0];
    const float* fc1_w = (const float*)d_in[1];
    const float* fc1_b = (const float*)d_in[2];
    const float* wx1   = (const float*)d_in[3];
    const float* wh1   = (const float*)d_in[4];
    const float* b1    = (const float*)d_in[5];
    const float* wx2   = (const float*)d_in[6];
    const float* wh2   = (const float*)d_in[7];
    const float* b2    = (const float*)d_in[8];
    const float* fc2_w = (const float*)d_in[9];
    const float* fc2_b = (const float*)d_in[10];
    float* out = (float*)d_out;

    char* ws = (char*)d_ws;
    size_t off = 0;
    auto carve = [&](size_t bytes) -> char* {
        char* p = ws + off; off += (bytes + 255) & ~(size_t)255; return p;
    };
    half_t* obs16 = (half_t*)carve((size_t)512*64*512*2);   // 33.6 MB
    half_t* wx1c  = (half_t*)carve((size_t)4096*1024*2);
    half_t* wh1t  = (half_t*)carve((size_t)4096*1024*2);
    half_t* wx2c  = (half_t*)carve((size_t)4096*1024*2);
    half_t* wh2t  = (half_t*)carve((size_t)4096*1024*2);
    half_t* fc1c  = (half_t*)carve((size_t)1024*512*2);
    half_t* fc2c  = (half_t*)carve((size_t)1024*1024*2);
    half_t* preA1a= (half_t*)carve((size_t)512*4096*2);     // parity 0
    half_t* preA1b= (half_t*)carve((size_t)512*4096*2);     // parity 1
    half_t* preA2 = (half_t*)carve((size_t)512*4096*2);
    half_t* preB1 = (half_t*)carve((size_t)512*4096*2);
    half_t* preB2 = (half_t*)carve((size_t)512*4096*2);
    half_t* h0s   = (half_t*)carve((size_t)512*1024*2);
    half_t* h1s   = (half_t*)carve((size_t)512*1024*2);
    float*  h0f   = (float*) carve((size_t)512*1024*4);
    float*  h1f   = (float*) carve((size_t)512*1024*4);
    float*  c0    = (float*) carve((size_t)512*1024*4);
    float*  c1    = (float*) carve((size_t)512*1024*4);
    int*    flags = (int*)   carve((size_t)64*16*4);        // 4 KB

    const size_t X_bytes = (size_t)512*64*1024*2;           // 67 MB
    bool modeB = (off + X_bytes) <= ws_size;
    half_t* X = (half_t*)carve(modeB ? X_bytes : (size_t)512*1024*2);

    hipMemsetAsync(h1s, 0, (size_t)512*1024*2, stream);
    hipMemsetAsync(c0,  0, (size_t)512*1024*4, stream);
    hipMemsetAsync(c1,  0, (size_t)512*1024*4, stream);
    hipMemsetAsync(preB1, 0, (size_t)512*4096*2, stream);   // h0(-1)=0
    hipMemsetAsync(flags, 0, (size_t)64*16*4, stream);

    // one-time conversions
    cvt_f32_f16<<<8192, 256, 0, stream>>>(obs,   obs16, 512*64*512/8);
    cvt_f32_f16<<<2048, 256, 0, stream>>>(wx1,   wx1c,  4*1024*1024/8);
    cvt_f32_f16<<<2048, 256, 0, stream>>>(wx2,   wx2c,  4*1024*1024/8);
    cvt_f32_f16<<<256,  256, 0, stream>>>(fc1_w, fc1c,  1024*512/8);
    cvt_f32_f16<<<512,  256, 0, stream>>>(fc2_w, fc2c,  1024*1024/8);
    transpose_wh_cvt<<<dim3(16,16,8), 256, 0, stream>>>(wh1, wh2, wh1t, wh2t);

    GArgs Z{};
    auto ga = [](const half_t* A, int lda, const half_t* B, int ldb, int K,
                 const float* bias, void* C, int ldc, int outhalf) {
        GArgs g; g.A=A; g.B=B; g.bias=bias; g.C=C;
        g.lda=lda; g.ldb=ldb; g.K=K; g.ldc=ldc; g.outhalf=outhalf; return g;
    };

    if (modeB) {
        // X = obs @ fc1^T + b : M=32768, N=1024, K=512
        gemm_ms<<<256*8, 256, 0, stream>>>(
            ga(obs16, 512, fc1c, 512, 512, fc1_b, X, 1024, 1), Z, Z, 256, 1);
        // preA1 parity0 = X(0) @ wx1^T
        gemm_ms<<<4*32, 256, 0, stream>>>(
            ga(X, 65536, wx1c, 1024, 1024, nullptr, preA1a, 4096, 1), Z, Z, 4, 1);

        for (int st = 0; st < 64; ++st)
            step_kernel<<<512, 256, 0, stream>>>(
                X, wx1c, wx2c, wh1t, wh2t, b1, b2,
                preA1a, preA1b, preA2, preB1, preB2,
                h0s, h1s, h0f, h1f, c0, c1, flags, st);
        cells_final<<<128, 256, 0, stream>>>(preA2, preB2, b2, c1, h1s, h1f);
    } else {
        for (int st = 0; st < 64; ++st) {
            gemm_ms<<<4*8, 256, 0, stream>>>(
                ga(obs16 + (size_t)st*512, 64*512, fc1c, 512, 512, fc1_b, X, 1024, 1),
                Z, Z, 4, 1);
            gemm_ms<<<4*32*2, 256, 0, stream>>>(
                ga(X, 1024,   wx1c, 1024, 1024, nullptr, preA2, 4096, 1),
                ga(h0s, 1024, wh1t, 1024, 1024, nullptr, preB2, 4096, 1), Z, 4, 2);
            lstm_cell<<<512, 256, 0, stream>>>(preA2, preB2, b1, c0, h0s, h0f);
            gemm_ms<<<4*32*2, 256, 0, stream>>>(
                ga(h0s, 1024, wx2c, 1024, 1024, nullptr, preA2, 4096, 1),
                ga(h1s, 1024, wh2t, 1024, 1024, nullptr, preB2, 4096, 1), Z, 4, 2);
            lstm_cell<<<512, 256, 0, stream>>>(preA2, preB2, b2, c1, h1s, h1f);
        }
    }

    // fc2: logit = h1 @ fc2_w^T + fc2_b -> d_out[0 : 512*1024) fp32
    gemm_ms<<<4*8, 256, 0, stream>>>(
        ga(h1s, 1024, fc2c, 1024, 1024, fc2_b, out, 1024, 0), Z, Z, 4, 1);
    pack_out<<<2048, 256, 0, stream>>>(h0f, h1f, c0, c1, out);
}

// Round 11
// 2625.554 us; speedup vs baseline: 1.5765x; 1.5765x over previous
//
#include <hip/hip_runtime.h>
#include <hip/hip_bf16.h>
#include <hip/hip_fp16.h>

using half_t = _Float16;
typedef __attribute__((ext_vector_type(8))) _Float16 f16x8;  // 8 fp16 = 4 VGPRs (MFMA frag)
typedef __attribute__((ext_vector_type(4))) _Float16 f16x4;
typedef __attribute__((ext_vector_type(4))) float f32x4;

#define LN_EPS 1e-5f

// async global->LDS, 16B per lane. gptr is PER-LANE, ldsbase is wave-uniform;
// HW writes ldsbase + lane*16.  [m97/m173 pattern]
__device__ inline void gll16(const void* g, void* ldsbase) {
    __builtin_amdgcn_global_load_lds(
        (const __attribute__((address_space(1))) void*)g,
        (__attribute__((address_space(3))) void*)ldsbase, 16, 0, 0);
}

// ---------------------------------------------------------------------------
// Wave-scope LN-LSTM cell: one 64-lane wave owns one batch row (16 elems/lane).
// ALL loads/stores plain (producers/consumers are in different launches).
// ---------------------------------------------------------------------------
__device__ inline void cell_wave(
    int b, int l,
    const half_t* __restrict__ pa, const half_t* __restrict__ pb,
    const float* __restrict__ bias,
    float* __restrict__ cst, half_t* __restrict__ hs,
    float* __restrict__ hf, bool final_step)
{
    float cn[16], og[16];
    float s = 0.f;
    #pragma unroll
    for (int j = 0; j < 4; ++j) {
        const int e = j*256 + l*4;
        const size_t pbase = (size_t)b*4096 + e;
        f16x4 a0 = *(const f16x4*)&pa[pbase];
        f16x4 a1 = *(const f16x4*)&pa[pbase + 1024];
        f16x4 a2 = *(const f16x4*)&pa[pbase + 2048];
        f16x4 a3 = *(const f16x4*)&pa[pbase + 3072];
        f16x4 q0 = *(const f16x4*)&pb[pbase];
        f16x4 q1 = *(const f16x4*)&pb[pbase + 1024];
        f16x4 q2 = *(const f16x4*)&pb[pbase + 2048];
        f16x4 q3 = *(const f16x4*)&pb[pbase + 3072];
        float4 b0 = *(const float4*)&bias[e];
        float4 b1v = *(const float4*)&bias[1024 + e];
        float4 b2v = *(const float4*)&bias[2048 + e];
        float4 b3v = *(const float4*)&bias[3072 + e];
        float4 c4 = *(const float4*)&cst[(size_t)b*1024 + e];
        const float* bp0 = (const float*)&b0;
        const float* bp1 = (const float*)&b1v;
        const float* bp2 = (const float*)&b2v;
        const float* bp3 = (const float*)&b3v;
        const float* cp  = (const float*)&c4;
        #pragma unroll
        for (int k = 0; k < 4; ++k) {
            float pi = (float)a0[k] + (float)q0[k] + bp0[k];
            float pf = (float)a1[k] + (float)q1[k] + bp1[k];
            float po = (float)a2[k] + (float)q2[k] + bp2[k];
            float pc = (float)a3[k] + (float)q3[k] + bp3[k];
            float ig = 1.f / (1.f + expf(-pi));
            float fg = 1.f / (1.f + expf(-pf));
            og[j*4+k] = 1.f / (1.f + expf(-po));
            float ct = tanhf(pc);
            float cv = fg * cp[k] + ig * ct;
            cn[j*4+k] = cv; s += cv;
        }
    }
    #pragma unroll
    for (int off = 1; off < 64; off <<= 1) s += __shfl_xor(s, off, 64);
    const float mu = s * (1.f/1024.f);
    float vs = 0.f;
    #pragma unroll
    for (int i = 0; i < 16; ++i) { float d = cn[i] - mu; vs += d*d; }
    #pragma unroll
    for (int off = 1; off < 64; off <<= 1) vs += __shfl_xor(vs, off, 64);
    const float rs = rsqrtf(vs * (1.f/1024.f) + LN_EPS);
    #pragma unroll
    for (int j = 0; j < 4; ++j) {
        const int e = j*256 + l*4;
        f16x4 h4; float4 hf4, c4;
        float* hfp = (float*)&hf4; float* cp = (float*)&c4;
        #pragma unroll
        for (int k = 0; k < 4; ++k) {
            float cv = (cn[j*4+k] - mu) * rs;
            float hv = og[j*4+k] * tanhf(cv);
            h4[k] = (half_t)hv;
            hfp[k] = hv; cp[k] = cv;
        }
        *(float4*)&cst[(size_t)b*1024 + e] = c4;
        *(f16x4*)&hs[(size_t)b*1024 + e]  = h4;
        if (final_step) *(float4*)&hf[(size_t)b*1024 + e] = hf4;
    }
}

// ---------------------------------------------------------------------------
// cells(t): WGs 0..127 -> cell1(t) rows; WGs 128..255 -> cell2(t-1) rows.
// Both independent (inputs all from earlier launches).
// ---------------------------------------------------------------------------
__global__ __launch_bounds__(256) void cells_kernel(
    const half_t* __restrict__ preA1_rd, const half_t* __restrict__ preB1,
    const half_t* __restrict__ preA2,    const half_t* __restrict__ preB2,
    const float* __restrict__ b1, const float* __restrict__ b2,
    float* __restrict__ c0, float* __restrict__ c1,
    half_t* __restrict__ h0s, half_t* __restrict__ h1s,
    float* __restrict__ h0f, float* __restrict__ h1f, int st)
{
    const int wg = blockIdx.x, l = threadIdx.x & 63, w = threadIdx.x >> 6;
    if (wg < 128) {
        cell_wave(wg*4 + w, l, preA1_rd, preB1, b1, c0, h0s, h0f, st == 63);
    } else if (st > 0) {
        cell_wave((wg-128)*4 + w, l, preA2, preB2, b2, c1, h1s, h1f, false);
    }
}

// ---------------------------------------------------------------------------
// gemms(t): 512 WGs, one full-machine round. wg = ylo + 8*(x + 4*(z + 4*yhi)):
//   z0: preA2(t)   = h0(t)   @ wx2^T
//   z1: preB2(t)   = h1(t-1) @ wh2^T
//   z2: preB1(t+1) = h0(t)   @ wh1^T
//   z3: preA1(t+1) = X(t+1)  @ wx1^T   (skipped at st==63)
// All operands from earlier launches -> plain global_load_lds everywhere.
// y%8 == dispatch%8 -> weight panels XCD-pinned across all 64 steps.
// ---------------------------------------------------------------------------
__global__ __launch_bounds__(256, 2) void step_gemm4(
    const half_t* __restrict__ X,
    const half_t* __restrict__ wx1c, const half_t* __restrict__ wx2c,
    const half_t* __restrict__ wh1t, const half_t* __restrict__ wh2t,
    half_t* __restrict__ preA1_wr, half_t* __restrict__ preA2,
    half_t* __restrict__ preB1, half_t* __restrict__ preB2,
    const half_t* __restrict__ h0s, const half_t* __restrict__ h1s, int st)
{
    __shared__ __align__(16) unsigned char sA[2][16384];
    __shared__ __align__(16) unsigned char sB[2][16384];

    const int wg = blockIdx.x;
    const int ylo = wg & 7;
    int r = wg >> 3;
    const int x = r & 3; r >>= 2;
    const int z = r & 3; r >>= 2;
    const int y = ylo + 8 * r;

    if (z == 3 && st == 63) return;      // no t+1

    const half_t* A; const half_t* B; half_t* C; size_t lda;
    if (z == 0)      { A = h0s; lda = 1024; B = wx2c; C = preA2; }
    else if (z == 1) { A = h1s; lda = 1024; B = wh2t; C = preB2; }
    else if (z == 2) { A = h0s; lda = 1024; B = wh1t; C = preB1; }
    else { A = X + (size_t)(st+1) * 1024; lda = 65536; B = wx1c; C = preA1_wr; }

    const int t = threadIdx.x, l = t & 63, w = t >> 6;
    const int wr = (w >> 1) * 64, wc = (w & 1) * 64;
    const int rowbase = x * 128, colbase = y * 128;

    int srow[4], sch[4];
    #pragma unroll
    for (int i = 0; i < 4; ++i) {
        int s = (w*4 + i)*64 + l;
        srow[i] = s >> 3;
        sch[i]  = ((s & 7) ^ (srow[i] & 7)) * 8;
    }

    f32x4 acc[4][4];
    #pragma unroll
    for (int m = 0; m < 4; ++m)
        #pragma unroll
        for (int n = 0; n < 4; ++n) acc[m][n] = (f32x4)(0.f);

    auto stage = [&](int kt, int buf) {
        const int ko = kt * 64;
        #pragma unroll
        for (int i = 0; i < 4; ++i) {
            gll16(A + (size_t)(rowbase+srow[i])*lda + ko + sch[i], &sA[buf][(w*4+i)*1024]);
            gll16(B + (size_t)(colbase+srow[i])*1024 + ko + sch[i], &sB[buf][(w*4+i)*1024]);
        }
    };

    stage(0, 0);
    for (int kt = 0; kt < 16; ++kt) {
        const int buf = kt & 1;
        __syncthreads();                 // vmcnt(0): buf ready; WAR-safe for buf^1
        if (kt + 1 < 16) stage(kt + 1, buf ^ 1);
        #pragma unroll
        for (int kk = 0; kk < 2; ++kk) {
            const int chunk = kk*4 + (l >> 4);
            f16x8 bfr[4];
            #pragma unroll
            for (int n = 0; n < 4; ++n) {
                int rowb = wc + n*16 + (l & 15);
                bfr[n] = *(const f16x8*)&sB[buf][rowb*128 + ((chunk ^ (rowb & 7)) << 4)];
            }
            #pragma unroll
            for (int m = 0; m < 4; ++m) {
                int rowa = wr + m*16 + (l & 15);
                f16x8 af = *(const f16x8*)&sA[buf][rowa*128 + ((chunk ^ (rowa & 7)) << 4)];
                #pragma unroll
                for (int n = 0; n < 4; ++n)
                    acc[m][n] = __builtin_amdgcn_mfma_f32_16x16x32_f16(af, bfr[n], acc[m][n], 0, 0, 0);
            }
        }
    }

    // epilogue: C/D layout col = lane&15, row = (lane>>4)*4 + reg  [m89/m91]
    #pragma unroll
    for (int m = 0; m < 4; ++m) {
        int row0 = rowbase + wr + m*16 + (l >> 4)*4;
        #pragma unroll
        for (int n = 0; n < 4; ++n) {
            int col = colbase + wc + n*16 + (l & 15);
            #pragma unroll
            for (int r2 = 0; r2 < 4; ++r2)
                C[(size_t)(row0+r2)*4096 + col] = (half_t)acc[m][n][r2];
        }
    }
}

// final cell2(63)
__global__ __launch_bounds__(256) void cells_final(
    const half_t* __restrict__ preA2, const half_t* __restrict__ preB2,
    const float* __restrict__ b2,
    float* __restrict__ c1, half_t* __restrict__ h1s, float* __restrict__ h1f)
{
    cell_wave(blockIdx.x*4 + (threadIdx.x >> 6), threadIdx.x & 63,
              preA2, preB2, b2, c1, h1s, h1f, true);
}

struct GArgs {
    const half_t* A; const half_t* B; const float* bias; void* C;
    int lda, ldb, K, ldc, outhalf;
};

// ---------------------------------------------------------------------------
// Multi-set fp16 GEMM (prologue / fc2 / fallback): up to 3 independent C=A*B^T.
// ---------------------------------------------------------------------------
__global__ __launch_bounds__(256) void gemm_ms(GArgs g0, GArgs g1, GArgs g2,
                                               int gx, int gz)
{
    const int d   = blockIdx.x;
    const int ylo = d & 7;
    int r   = d >> 3;
    const int x  = r % gx;  r /= gx;
    const int z  = r % gz;
    const int y  = ylo + 8 * (r / gz);

    const GArgs g = (z == 0) ? g0 : (z == 1 ? g1 : g2);

    __shared__ __align__(16) unsigned char sA[2][16384];
    __shared__ __align__(16) unsigned char sB[2][16384];

    const int t  = threadIdx.x;
    const int l  = t & 63;
    const int w  = t >> 6;
    const int wr = (w >> 1) * 64;
    const int wc = (w & 1)  * 64;
    const int rowbase = x * 128;
    const int colbase = y * 128;

    f32x4 acc[4][4];
    #pragma unroll
    for (int m = 0; m < 4; ++m)
        #pragma unroll
        for (int n = 0; n < 4; ++n) acc[m][n] = (f32x4)(0.f);

    int srow[4], sch[4];
    #pragma unroll
    for (int i = 0; i < 4; ++i) {
        int s = (w*4 + i)*64 + l;
        srow[i] = s >> 3;
        sch[i]  = ((s & 7) ^ (srow[i] & 7)) * 8;
    }

    const int nkt = g.K >> 6;

    auto stage = [&](int kt, int buf) {
        const int ko = kt * 64;
        #pragma unroll
        for (int i = 0; i < 4; ++i) {
            gll16(g.A + (size_t)(rowbase+srow[i])*g.lda + ko + sch[i], &sA[buf][(w*4+i)*1024]);
            gll16(g.B + (size_t)(colbase+srow[i])*g.ldb + ko + sch[i], &sB[buf][(w*4+i)*1024]);
        }
    };

    stage(0, 0);
    for (int kt = 0; kt < nkt; ++kt) {
        const int buf = kt & 1;
        __syncthreads();
        if (kt + 1 < nkt) stage(kt + 1, buf ^ 1);
        #pragma unroll
        for (int kk = 0; kk < 2; ++kk) {
            const int chunk = kk*4 + (l >> 4);
            f16x8 bfr[4];
            #pragma unroll
            for (int n = 0; n < 4; ++n) {
                int rowb = wc + n*16 + (l & 15);
                bfr[n] = *(const f16x8*)&sB[buf][rowb*128 + ((chunk ^ (rowb & 7)) << 4)];
            }
            #pragma unroll
            for (int m = 0; m < 4; ++m) {
                int rowa = wr + m*16 + (l & 15);
                f16x8 af = *(const f16x8*)&sA[buf][rowa*128 + ((chunk ^ (rowa & 7)) << 4)];
                #pragma unroll
                for (int n = 0; n < 4; ++n)
                    acc[m][n] = __builtin_amdgcn_mfma_f32_16x16x32_f16(af, bfr[n], acc[m][n], 0, 0, 0);
            }
        }
    }

    #pragma unroll
    for (int m = 0; m < 4; ++m) {
        int row0 = rowbase + wr + m*16 + (l >> 4)*4;
        #pragma unroll
        for (int n = 0; n < 4; ++n) {
            int col = colbase + wc + n*16 + (l & 15);
            float bv = g.bias ? g.bias[col] : 0.f;
            #pragma unroll
            for (int r2 = 0; r2 < 4; ++r2) {
                float v = acc[m][n][r2] + bv;
                if (g.outhalf) ((half_t*)g.C)[(size_t)(row0+r2)*g.ldc + col] = (half_t)v;
                else           ((float*)g.C)[(size_t)(row0+r2)*g.ldc + col] = v;
            }
        }
    }
}

// ---------------------------------------------------------------------------
__global__ __launch_bounds__(256) void transpose_wh_cvt(
    const float* __restrict__ wh1, const float* __restrict__ wh2,
    half_t* __restrict__ o1, half_t* __restrict__ o2)
{
    __shared__ float tile[64][65];
    const int z = blockIdx.z;
    const float* src = (z < 4 ? wh1 : wh2) + (size_t)(z & 3) * 1024 * 1024;
    half_t*      dst = (z < 4 ? o1  : o2 ) + (size_t)(z & 3) * 1024 * 1024;
    const int kb = blockIdx.x * 64, nb = blockIdx.y * 64;
    const int t = threadIdx.x;
    #pragma unroll
    for (int i = 0; i < 16; ++i) {
        int idx = t + i*256, r = idx >> 6, c = idx & 63;
        tile[r][c] = src[(size_t)(kb + r)*1024 + nb + c];
    }
    __syncthreads();
    #pragma unroll
    for (int i = 0; i < 16; ++i) {
        int idx = t + i*256, r = idx >> 6, c = idx & 63;
        dst[(size_t)(nb + r)*1024 + kb + c] = (half_t)tile[c][r];
    }
}

__global__ __launch_bounds__(256) void cvt_f32_f16(
    const float* __restrict__ in, half_t* __restrict__ out, int n8)
{
    int i = blockIdx.x * 256 + threadIdx.x;
    if (i >= n8) return;
    float4 lo = ((const float4*)in)[2*i];
    float4 hi = ((const float4*)in)[2*i + 1];
    union { uint4 v; half_t h[8]; } r;
    r.h[0]=(half_t)lo.x; r.h[1]=(half_t)lo.y; r.h[2]=(half_t)lo.z; r.h[3]=(half_t)lo.w;
    r.h[4]=(half_t)hi.x; r.h[5]=(half_t)hi.y; r.h[6]=(half_t)hi.z; r.h[7]=(half_t)hi.w;
    ((uint4*)out)[i] = r.v;
}

__global__ __launch_bounds__(256) void pack_out(
    const float* __restrict__ h0, const float* __restrict__ h1,
    const float* __restrict__ c0, const float* __restrict__ c1, float* __restrict__ out)
{
    const int NSZ = 512 * 1024;
    int i = blockIdx.x * 256 + threadIdx.x;
    out[NSZ     + i] = h0[i];
    out[2*NSZ   + i] = h1[i];
    out[3*NSZ   + i] = c0[i];
    out[4*NSZ   + i] = c1[i];
}

extern "C" void kernel_launch(void* const* d_in, const int* in_sizes, int n_in,
                              void* d_out, int out_size, void* d_ws, size_t ws_size,
                              hipStream_t stream)
{
    const float* obs   = (const float*)d_in[0];
    const float* fc1_w = (const float*)d_in[1];
    const float* fc1_b = (const float*)d_in[2];
    const float* wx1   = (const float*)d_in[3];
    const float* wh1   = (const float*)d_in[4];
    const float* b1    = (const float*)d_in[5];
    const float* wx2   = (const float*)d_in[6];
    const float* wh2   = (const float*)d_in[7];
    const float* b2    = (const float*)d_in[8];
    const float* fc2_w = (const float*)d_in[9];
    const float* fc2_b = (const float*)d_in[10];
    float* out = (float*)d_out;

    char* ws = (char*)d_ws;
    size_t off = 0;
    auto carve = [&](size_t bytes) -> char* {
        char* p = ws + off; off += (bytes + 255) & ~(size_t)255; return p;
    };
    half_t* obs16 = (half_t*)carve((size_t)512*64*512*2);   // 33.6 MB
    half_t* wx1c  = (half_t*)carve((size_t)4096*1024*2);
    half_t* wh1t  = (half_t*)carve((size_t)4096*1024*2);
    half_t* wx2c  = (half_t*)carve((size_t)4096*1024*2);
    half_t* wh2t  = (half_t*)carve((size_t)4096*1024*2);
    half_t* fc1c  = (half_t*)carve((size_t)1024*512*2);
    half_t* fc2c  = (half_t*)carve((size_t)1024*1024*2);
    half_t* preA1a= (half_t*)carve((size_t)512*4096*2);     // parity 0
    half_t* preA1b= (half_t*)carve((size_t)512*4096*2);     // parity 1
    half_t* preA2 = (half_t*)carve((size_t)512*4096*2);
    half_t* preB1 = (half_t*)carve((size_t)512*4096*2);
    half_t* preB2 = (half_t*)carve((size_t)512*4096*2);
    half_t* h0s   = (half_t*)carve((size_t)512*1024*2);
    half_t* h1s   = (half_t*)carve((size_t)512*1024*2);
    float*  h0f   = (float*) carve((size_t)512*1024*4);
    float*  h1f   = (float*) carve((size_t)512*1024*4);
    float*  c0    = (float*) carve((size_t)512*1024*4);
    float*  c1    = (float*) carve((size_t)512*1024*4);

    const size_t X_bytes = (size_t)512*64*1024*2;           // 67 MB
    bool modeB = (off + X_bytes) <= ws_size;
    half_t* X = (half_t*)carve(modeB ? X_bytes : (size_t)512*1024*2);

    hipMemsetAsync(h1s, 0, (size_t)512*1024*2, stream);
    hipMemsetAsync(c0,  0, (size_t)512*1024*4, stream);
    hipMemsetAsync(c1,  0, (size_t)512*1024*4, stream);
    hipMemsetAsync(preB1, 0, (size_t)512*4096*2, stream);   // h0(-1)=0

    // one-time conversions
    cvt_f32_f16<<<8192, 256, 0, stream>>>(obs,   obs16, 512*64*512/8);
    cvt_f32_f16<<<2048, 256, 0, stream>>>(wx1,   wx1c,  4*1024*1024/8);
    cvt_f32_f16<<<2048, 256, 0, stream>>>(wx2,   wx2c,  4*1024*1024/8);
    cvt_f32_f16<<<256,  256, 0, stream>>>(fc1_w, fc1c,  1024*512/8);
    cvt_f32_f16<<<512,  256, 0, stream>>>(fc2_w, fc2c,  1024*1024/8);
    transpose_wh_cvt<<<dim3(16,16,8), 256, 0, stream>>>(wh1, wh2, wh1t, wh2t);

    GArgs Z{};
    auto ga = [](const half_t* A, int lda, const half_t* B, int ldb, int K,
                 const float* bias, void* C, int ldc, int outhalf) {
        GArgs g; g.A=A; g.B=B; g.bias=bias; g.C=C;
        g.lda=lda; g.ldb=ldb; g.K=K; g.ldc=ldc; g.outhalf=outhalf; return g;
    };

    if (modeB) {
        // X = obs @ fc1^T + b : M=32768, N=1024, K=512
        gemm_ms<<<256*8, 256, 0, stream>>>(
            ga(obs16, 512, fc1c, 512, 512, fc1_b, X, 1024, 1), Z, Z, 256, 1);
        // preA1 parity0 = X(0) @ wx1^T
        gemm_ms<<<4*32, 256, 0, stream>>>(
            ga(X, 65536, wx1c, 1024, 1024, nullptr, preA1a, 4096, 1), Z, Z, 4, 1);

        for (int st = 0; st < 64; ++st) {
            const half_t* preA1_rd = (st & 1) ? preA1b : preA1a;
            half_t*       preA1_wr = (st & 1) ? preA1a : preA1b;
            cells_kernel<<<256, 256, 0, stream>>>(
                preA1_rd, preB1, preA2, preB2, b1, b2,
                c0, c1, h0s, h1s, h0f, h1f, st);
            step_gemm4<<<512, 256, 0, stream>>>(
                X, wx1c, wx2c, wh1t, wh2t,
                preA1_wr, preA2, preB1, preB2, h0s, h1s, st);
        }
        cells_final<<<128, 256, 0, stream>>>(preA2, preB2, b2, c1, h1s, h1f);
    } else {
        // fallback: per-step small GEMMs (correct, slower)
        for (int st = 0; st < 64; ++st) {
            gemm_ms<<<4*8, 256, 0, stream>>>(
                ga(obs16 + (size_t)st*512, 64*512, fc1c, 512, 512, fc1_b, X, 1024, 1),
                Z, Z, 4, 1);
            gemm_ms<<<4*32*2, 256, 0, stream>>>(
                ga(X, 1024,   wx1c, 1024, 1024, nullptr, preA1a, 4096, 1),
                ga(h0s, 1024, wh1t, 1024, 1024, nullptr, preB1, 4096, 1), Z, 4, 2);
            cells_kernel<<<256, 256, 0, stream>>>(
                preA1a, preB1, preA2, preB2, b1, b2,
                c0, c1, h0s, h1s, h0f, h1f, st == 63 ? 63 : (st > 0 ? st : 0));
            gemm_ms<<<4*32*2, 256, 0, stream>>>(
                ga(h0s, 1024, wx2c, 1024, 1024, nullptr, preA2, 4096, 1),
                ga(h1s, 1024, wh2t, 1024, 1024, nullptr, preB2, 4096, 1), Z, 4, 2);
        }
        cells_final<<<128, 256, 0, stream>>>(preA2, preB2, b2, c1, h1s, h1f);
    }

    // fc2: logit = h1 @ fc2_w^T + fc2_b -> d_out[0 : 512*1024) fp32
    gemm_ms<<<4*8, 256, 0, stream>>>(
        ga(h1s, 1024, fc2c, 1024, 1024, fc2_b, out, 1024, 0), Z, Z, 4, 1);
    pack_out<<<2048, 256, 0, stream>>>(h0f, h1f, c0, c1, out);
}